// Round 1
// baseline (237.721 us; speedup 1.0000x reference)
//
#include <hip/hip_runtime.h>
#include <hip/hip_bf16.h>
#include <math.h>

#define N_PROP 600
#define NUM_CLS 151
#define FEAT_DIM 4096
#define K_OUT 100
#define SCORE_THRESH 0.05f
#define NMS_THRESH 0.5f
#define PER_CLS_TOPN 300
#define IMG_W 1024.0f
#define IMG_H 768.0f
#define BBOX_CLIP 4.135166556742356f  /* log(1000/16) */
#define MAXW 10                       /* ceil(600/64) */

// ---------------------------------------------------------------------------
// Kernel A: softmax over classes + box decode + clip.  One block per proposal.
// ---------------------------------------------------------------------------
__global__ __launch_bounds__(256) void decode_softmax_kernel(
    const float* __restrict__ logits, const float* __restrict__ breg,
    const float* __restrict__ pboxes, float* __restrict__ probs,
    float* __restrict__ boxes) {
  int n = blockIdx.x;
  int c = threadIdx.x;
  __shared__ float red[256];

  float x = (c < NUM_CLS) ? logits[n * NUM_CLS + c] : -INFINITY;
  red[c] = x;
  __syncthreads();
  for (int s = 128; s > 0; s >>= 1) {
    if (c < s) red[c] = fmaxf(red[c], red[c + s]);
    __syncthreads();
  }
  float mx = red[0];
  __syncthreads();
  float e = (c < NUM_CLS) ? expf(x - mx) : 0.0f;
  red[c] = e;
  __syncthreads();
  for (int s = 128; s > 0; s >>= 1) {
    if (c < s) red[c] += red[c + s];
    __syncthreads();
  }
  float sum = red[0];

  if (c < NUM_CLS) {
    probs[n * NUM_CLS + c] = e / sum;

    float b0 = pboxes[n * 4 + 0], b1 = pboxes[n * 4 + 1];
    float b2 = pboxes[n * 4 + 2], b3 = pboxes[n * 4 + 3];
    float w = b2 - b0 + 1.0f, h = b3 - b1 + 1.0f;
    float cx = b0 + 0.5f * w, cy = b1 + 0.5f * h;
    const float* d = breg + (size_t)n * (NUM_CLS * 4) + c * 4;
    float dx = d[0] / 10.0f, dy = d[1] / 10.0f;
    float dw = fminf(d[2] / 5.0f, BBOX_CLIP);
    float dh = fminf(d[3] / 5.0f, BBOX_CLIP);
    float pcx = dx * w + cx, pcy = dy * h + cy;
    float pw = expf(dw) * w, ph = expf(dh) * h;
    float x1 = pcx - 0.5f * pw, y1 = pcy - 0.5f * ph;
    float x2 = pcx + 0.5f * pw - 1.0f, y2 = pcy + 0.5f * ph - 1.0f;
    x1 = fminf(fmaxf(x1, 0.0f), IMG_W - 1.0f);
    y1 = fminf(fmaxf(y1, 0.0f), IMG_H - 1.0f);
    x2 = fminf(fmaxf(x2, 0.0f), IMG_W - 1.0f);
    y2 = fminf(fmaxf(y2, 0.0f), IMG_H - 1.0f);
    float4* bo = (float4*)(boxes + (size_t)(n * NUM_CLS + c) * 4);
    *bo = make_float4(x1, y1, x2, y2);
  }
}

// ---------------------------------------------------------------------------
// Kernel B: per-class greedy NMS.  One block per class (class 0 = background,
// only zeroes its column).  Compact -> bitonic sort -> wave-ballot IoU mask ->
// serial bitmask scan (exactly matches reference fori_loop semantics:
// suppression uses ALL keeps, the 300-cap masks output flags only).
// ---------------------------------------------------------------------------
__global__ __launch_bounds__(256) void nms_kernel(
    const float* __restrict__ probs, const float* __restrict__ boxes,
    unsigned char* __restrict__ kept) {
  int j = blockIdx.x;
  int t = threadIdx.x;

  for (int n = t; n < N_PROP; n += 256) kept[j * N_PROP + n] = 0;
  if (j == 0) return;

  __shared__ int s_m;
  // LDS pool: [0,48000) keys (phase 1, 1024*8B) then IoU mask (600*10*8B);
  // [48000,57600) boxes float4; [57600,58800) idx u16; [58800,...) keep flags
  alignas(16) __shared__ unsigned char pool[48000 + 9600 + 1280 + 640];
  unsigned long long* s_key  = (unsigned long long*)pool;
  unsigned long long* s_mask = (unsigned long long*)pool;
  float4*             s_box  = (float4*)(pool + 48000);
  unsigned short*     s_idx  = (unsigned short*)(pool + 48000 + 9600);
  unsigned char*      s_keep = pool + 48000 + 9600 + 1280;

  if (t == 0) s_m = 0;
  __syncthreads();
  for (int n = t; n < N_PROP; n += 256) {
    float p = probs[n * NUM_CLS + j];
    if (p > SCORE_THRESH) {
      int pos = atomicAdd(&s_m, 1);
      // score desc, index asc when sorted ascending (scores are positive)
      s_key[pos] = ((unsigned long long)(~__float_as_uint(p)) << 32) | (unsigned)n;
    }
  }
  __syncthreads();
  int m = s_m;
  if (m == 0) return;

  int sz = 1;
  while (sz < m) sz <<= 1;
  for (int i = m + t; i < sz; i += 256) s_key[i] = ~0ULL;
  __syncthreads();

  for (int k = 2; k <= sz; k <<= 1) {
    for (int len = k >> 1; len > 0; len >>= 1) {
      for (int i = t; i < sz; i += 256) {
        int p2 = i ^ len;
        if (p2 > i) {
          unsigned long long a = s_key[i], b = s_key[p2];
          bool up = ((i & k) == 0);
          if ((a > b) == up) { s_key[i] = b; s_key[p2] = a; }
        }
      }
      __syncthreads();
    }
  }

  // extract indices + load sorted boxes (keys still live; mask not written yet)
  for (int i = t; i < m; i += 256) {
    int n = (int)(s_key[i] & 0xFFFFFFFFULL);
    s_idx[i] = (unsigned short)n;
    s_box[i] = *(const float4*)(boxes + (size_t)(n * NUM_CLS + j) * 4);
  }
  __syncthreads();  // after this, mask writes may clobber the key region

  int words = (m + 63) >> 6;
  int wave = t >> 6, lane = t & 63;
  for (int i = wave; i < m; i += 4) {
    float4 bi = s_box[i];
    float ai = (bi.z - bi.x + 1.0f) * (bi.w - bi.y + 1.0f);
    for (int w = 0; w < words; ++w) {
      int jj = (w << 6) + lane;
      bool over = false;
      if (jj < m) {
        float4 bj = s_box[jj];
        float xx1 = fmaxf(bi.x, bj.x), yy1 = fmaxf(bi.y, bj.y);
        float xx2 = fminf(bi.z, bj.z), yy2 = fminf(bi.w, bj.w);
        float iw = fmaxf(xx2 - xx1 + 1.0f, 0.0f);
        float ih = fmaxf(yy2 - yy1 + 1.0f, 0.0f);
        float inter = iw * ih;
        float aj = (bj.z - bj.x + 1.0f) * (bj.w - bj.y + 1.0f);
        over = (inter / (ai + aj - inter)) > NMS_THRESH;
      }
      unsigned long long bal = __ballot(over);
      if (lane == 0) s_mask[(size_t)i * words + w] = bal;
    }
  }
  __syncthreads();

  if (t == 0) {
    unsigned long long removed[MAXW];
    for (int w = 0; w < words; ++w) removed[w] = 0ULL;
    int cnt = 0;
    for (int i = 0; i < m; ++i) {
      if (!((removed[i >> 6] >> (i & 63)) & 1ULL)) {
        ++cnt;
        s_keep[i] = (cnt <= PER_CLS_TOPN) ? 1 : 0;
        const unsigned long long* row = s_mask + (size_t)i * words;
        for (int w = 0; w < words; ++w) removed[w] |= row[w];
      } else {
        s_keep[i] = 0;
      }
    }
  }
  __syncthreads();
  for (int i = t; i < m; i += 256) {
    if (s_keep[i]) kept[j * N_PROP + s_idx[i]] = 1;
  }
}

// ---------------------------------------------------------------------------
// Kernel C: per-proposal max/argmax over kept classes, top-100 via bitonic
// sort (lax.top_k semantics: value desc, index asc on ties), write all small
// outputs + boxes_per_cls; stash top_idx / m for the feature gather.
// ---------------------------------------------------------------------------
__global__ __launch_bounds__(256) void combine_kernel(
    const float* __restrict__ probs, const float* __restrict__ boxes,
    const unsigned char* __restrict__ kept, float* __restrict__ out,
    int* __restrict__ top_idx_ws, float* __restrict__ top_m_ws) {
  int t = threadIdx.x;
  __shared__ float s_score[N_PROP];
  __shared__ int s_label[N_PROP];
  __shared__ unsigned long long s_key[1024];
  __shared__ int s_tidx[K_OUT];
  __shared__ float s_tm[K_OUT];

  for (int n = t; n < N_PROP; n += 256) {
    float best = 0.0f;  // dist[n][0] == 0 always
    int lab = 0;
    for (int c = 1; c < NUM_CLS; ++c) {
      if (kept[c * N_PROP + n]) {
        float v = probs[n * NUM_CLS + c];
        if (v > best) { best = v; lab = c; }   // strict > == argmax first-max
      }
    }
    s_score[n] = best;
    s_label[n] = lab;
    float sel = (best > 0.0f) ? best : -1.0f;
    unsigned int sb = __float_as_uint(sel);
    unsigned int mapped = (sb >> 31) ? ~sb : (sb | 0x80000000u);  // sortable
    s_key[n] = ((unsigned long long)(~mapped) << 32) | (unsigned)n;
  }
  for (int n = N_PROP + t; n < 1024; n += 256) s_key[n] = ~0ULL;
  __syncthreads();

  for (int k = 2; k <= 1024; k <<= 1) {
    for (int len = k >> 1; len > 0; len >>= 1) {
      for (int i = t; i < 1024; i += 256) {
        int p2 = i ^ len;
        if (p2 > i) {
          unsigned long long a = s_key[i], b = s_key[p2];
          bool up = ((i & k) == 0);
          if ((a > b) == up) { s_key[i] = b; s_key[p2] = a; }
        }
      }
      __syncthreads();
    }
  }

  const int OF_BOX = K_OUT * FEAT_DIM;     // 409600
  const int OF_SC  = OF_BOX + K_OUT * 4;   // 410000
  const int OF_LB  = OF_SC + K_OUT;        // 410100
  const int OF_VD  = OF_LB + K_OUT;        // 410200
  const int OF_BPC = OF_VD + K_OUT;        // 410300

  if (t < K_OUT) {
    int n = (int)(s_key[t] & 0xFFFFFFFFULL);
    float v = s_score[n];
    bool valid = v > 0.0f;
    float mm = valid ? 1.0f : 0.0f;
    int glab = s_label[n];                 // top_labels (used for box gather)
    out[OF_SC + t] = valid ? v : 0.0f;
    out[OF_LB + t] = (float)(valid ? glab : 0);
    out[OF_VD + t] = mm;
    const float* bp = boxes + (size_t)(n * NUM_CLS + glab) * 4;
    out[OF_BOX + t * 4 + 0] = bp[0] * mm;
    out[OF_BOX + t * 4 + 1] = bp[1] * mm;
    out[OF_BOX + t * 4 + 2] = bp[2] * mm;
    out[OF_BOX + t * 4 + 3] = bp[3] * mm;
    s_tidx[t] = n;
    s_tm[t] = mm;
    top_idx_ws[t] = n;
    top_m_ws[t] = mm;
  }
  __syncthreads();

  for (int q = t; q < K_OUT * NUM_CLS; q += 256) {
    int k = q / NUM_CLS, c = q % NUM_CLS;
    int n = s_tidx[k];
    float mm = s_tm[k];
    float4 b = *(const float4*)(boxes + (size_t)(n * NUM_CLS + c) * 4);
    float* o = out + OF_BPC + (size_t)q * 4;
    o[0] = b.x * mm; o[1] = b.y * mm; o[2] = b.z * mm; o[3] = b.w * mm;
  }
}

// ---------------------------------------------------------------------------
// Kernel D: gather features rows for the top-100.  One block per output row.
// ---------------------------------------------------------------------------
__global__ __launch_bounds__(256) void gather_features_kernel(
    const float* __restrict__ features, const int* __restrict__ top_idx,
    const float* __restrict__ top_m, float* __restrict__ out) {
  int k = blockIdx.x;
  int n = top_idx[k];
  float mm = top_m[k];
  const float4* src = (const float4*)(features + (size_t)n * FEAT_DIM);
  float4* dst = (float4*)(out + (size_t)k * FEAT_DIM);
  for (int i = threadIdx.x; i < FEAT_DIM / 4; i += 256) {
    float4 v = src[i];
    dst[i] = make_float4(v.x * mm, v.y * mm, v.z * mm, v.w * mm);
  }
}

extern "C" void kernel_launch(void* const* d_in, const int* in_sizes, int n_in,
                              void* d_out, int out_size, void* d_ws, size_t ws_size,
                              hipStream_t stream) {
  const float* features = (const float*)d_in[0];
  const float* logits   = (const float*)d_in[1];
  const float* breg     = (const float*)d_in[2];
  const float* pboxes   = (const float*)d_in[3];
  float* out = (float*)d_out;

  // workspace layout
  float* probs = (float*)d_ws;                              // 600*151 f32
  float* boxes = probs + N_PROP * NUM_CLS;                  // 600*151*4 f32
  unsigned char* kept = (unsigned char*)(boxes + (size_t)N_PROP * NUM_CLS * 4);
  size_t kept_end = (size_t)(kept + NUM_CLS * N_PROP);
  int* top_idx = (int*)((kept_end + 15) & ~(size_t)15);
  float* top_m = (float*)(top_idx + 128);

  hipLaunchKernelGGL(decode_softmax_kernel, dim3(N_PROP), dim3(256), 0, stream,
                     logits, breg, pboxes, probs, boxes);
  hipLaunchKernelGGL(nms_kernel, dim3(NUM_CLS), dim3(256), 0, stream,
                     probs, boxes, kept);
  hipLaunchKernelGGL(combine_kernel, dim3(1), dim3(256), 0, stream,
                     probs, boxes, kept, out, top_idx, top_m);
  hipLaunchKernelGGL(gather_features_kernel, dim3(K_OUT), dim3(256), 0, stream,
                     features, top_idx, top_m, out);
}

// Round 2
// 113.264 us; speedup vs baseline: 2.0988x; 2.0988x over previous
//
#include <hip/hip_runtime.h>
#include <hip/hip_bf16.h>
#include <math.h>

#define N_PROP 600
#define NUM_CLS 151
#define FEAT_DIM 4096
#define K_OUT 100
#define SCORE_THRESH 0.05f
#define NMS_THRESH 0.5f
#define PER_CLS_TOPN 300
#define IMG_W 1024.0f
#define IMG_H 768.0f
#define BBOX_CLIP 4.135166556742356f  /* log(1000/16) */
#define MAXW 10                       /* ceil(600/64) */

// out layout (reference return order, all f32):
#define OF_BOX (K_OUT * FEAT_DIM)      /* 409600: final_boxes [100,4]   */
#define OF_SC  (OF_BOX + K_OUT * 4)    /* 410000: final_scores [100]    */
#define OF_LB  (OF_SC + K_OUT)         /* 410100: final_labels [100]    */
#define OF_VD  (OF_LB + K_OUT)         /* 410200: valid_out [100]       */
#define OF_BPC (OF_VD + K_OUT)         /* 410300: boxes_per_cls [100,151,4] */

// ---------------------------------------------------------------------------
// Kernel A: softmax + box decode + clip; also zeroes kept[n][*].
// One block per proposal.
// ---------------------------------------------------------------------------
__global__ __launch_bounds__(256) void decode_softmax_kernel(
    const float* __restrict__ logits, const float* __restrict__ breg,
    const float* __restrict__ pboxes, float* __restrict__ probs,
    float* __restrict__ boxes, unsigned char* __restrict__ kept) {
  int n = blockIdx.x;
  int c = threadIdx.x;
  __shared__ float red[256];

  if (c < NUM_CLS) kept[n * NUM_CLS + c] = 0;

  float x = (c < NUM_CLS) ? logits[n * NUM_CLS + c] : -INFINITY;
  red[c] = x;
  __syncthreads();
  for (int s = 128; s > 0; s >>= 1) {
    if (c < s) red[c] = fmaxf(red[c], red[c + s]);
    __syncthreads();
  }
  float mx = red[0];
  __syncthreads();
  float e = (c < NUM_CLS) ? expf(x - mx) : 0.0f;
  red[c] = e;
  __syncthreads();
  for (int s = 128; s > 0; s >>= 1) {
    if (c < s) red[c] += red[c + s];
    __syncthreads();
  }
  float sum = red[0];

  if (c < NUM_CLS) {
    probs[n * NUM_CLS + c] = e / sum;

    float b0 = pboxes[n * 4 + 0], b1 = pboxes[n * 4 + 1];
    float b2 = pboxes[n * 4 + 2], b3 = pboxes[n * 4 + 3];
    float w = b2 - b0 + 1.0f, h = b3 - b1 + 1.0f;
    float cx = b0 + 0.5f * w, cy = b1 + 0.5f * h;
    const float* d = breg + (size_t)n * (NUM_CLS * 4) + c * 4;
    float dx = d[0] / 10.0f, dy = d[1] / 10.0f;
    float dw = fminf(d[2] / 5.0f, BBOX_CLIP);
    float dh = fminf(d[3] / 5.0f, BBOX_CLIP);
    float pcx = dx * w + cx, pcy = dy * h + cy;
    float pw = expf(dw) * w, ph = expf(dh) * h;
    float x1 = pcx - 0.5f * pw, y1 = pcy - 0.5f * ph;
    float x2 = pcx + 0.5f * pw - 1.0f, y2 = pcy + 0.5f * ph - 1.0f;
    x1 = fminf(fmaxf(x1, 0.0f), IMG_W - 1.0f);
    y1 = fminf(fmaxf(y1, 0.0f), IMG_H - 1.0f);
    x2 = fminf(fmaxf(x2, 0.0f), IMG_W - 1.0f);
    y2 = fminf(fmaxf(y2, 0.0f), IMG_H - 1.0f);
    float4* bo = (float4*)(boxes + (size_t)(n * NUM_CLS + c) * 4);
    *bo = make_float4(x1, y1, x2, y2);
  }
}

// ---------------------------------------------------------------------------
// Kernel B: per-class greedy NMS.  One block per class (class 0 skipped —
// kept already zeroed).  Compact -> bitonic sort -> wave-ballot IoU mask ->
// serial bitmask scan (matches reference: suppression uses ALL keeps, the
// 300-cap masks output flags only).  Writes kept in [n][c] layout.
// ---------------------------------------------------------------------------
__global__ __launch_bounds__(256) void nms_kernel(
    const float* __restrict__ probs, const float* __restrict__ boxes,
    unsigned char* __restrict__ kept) {
  int j = blockIdx.x + 1;  // classes 1..150
  int t = threadIdx.x;

  __shared__ int s_m;
  // LDS pool: [0,48000) keys (phase 1, 1024*8B) then IoU mask (600*10*8B);
  // [48000,57600) boxes float4; [57600,58800) idx u16; [58800,...) keep flags
  alignas(16) __shared__ unsigned char pool[48000 + 9600 + 1280 + 640];
  unsigned long long* s_key  = (unsigned long long*)pool;
  unsigned long long* s_mask = (unsigned long long*)pool;
  float4*             s_box  = (float4*)(pool + 48000);
  unsigned short*     s_idx  = (unsigned short*)(pool + 48000 + 9600);
  unsigned char*      s_keep = pool + 48000 + 9600 + 1280;

  if (t == 0) s_m = 0;
  __syncthreads();
  for (int n = t; n < N_PROP; n += 256) {
    float p = probs[n * NUM_CLS + j];
    if (p > SCORE_THRESH) {
      int pos = atomicAdd(&s_m, 1);
      // score desc, index asc when sorted ascending (scores are positive)
      s_key[pos] = ((unsigned long long)(~__float_as_uint(p)) << 32) | (unsigned)n;
    }
  }
  __syncthreads();
  int m = s_m;
  if (m == 0) return;

  int sz = 1;
  while (sz < m) sz <<= 1;
  for (int i = m + t; i < sz; i += 256) s_key[i] = ~0ULL;
  __syncthreads();

  for (int k = 2; k <= sz; k <<= 1) {
    for (int len = k >> 1; len > 0; len >>= 1) {
      for (int i = t; i < sz; i += 256) {
        int p2 = i ^ len;
        if (p2 > i) {
          unsigned long long a = s_key[i], b = s_key[p2];
          bool up = ((i & k) == 0);
          if ((a > b) == up) { s_key[i] = b; s_key[p2] = a; }
        }
      }
      __syncthreads();
    }
  }

  // extract indices + load sorted boxes (keys still live; mask not written yet)
  for (int i = t; i < m; i += 256) {
    int n = (int)(s_key[i] & 0xFFFFFFFFULL);
    s_idx[i] = (unsigned short)n;
    s_box[i] = *(const float4*)(boxes + (size_t)(n * NUM_CLS + j) * 4);
  }
  __syncthreads();  // after this, mask writes may clobber the key region

  int words = (m + 63) >> 6;
  int wave = t >> 6, lane = t & 63;
  for (int i = wave; i < m; i += 4) {
    float4 bi = s_box[i];
    float ai = (bi.z - bi.x + 1.0f) * (bi.w - bi.y + 1.0f);
    for (int w = 0; w < words; ++w) {
      int jj = (w << 6) + lane;
      bool over = false;
      if (jj < m) {
        float4 bj = s_box[jj];
        float xx1 = fmaxf(bi.x, bj.x), yy1 = fmaxf(bi.y, bj.y);
        float xx2 = fminf(bi.z, bj.z), yy2 = fminf(bi.w, bj.w);
        float iw = fmaxf(xx2 - xx1 + 1.0f, 0.0f);
        float ih = fmaxf(yy2 - yy1 + 1.0f, 0.0f);
        float inter = iw * ih;
        float aj = (bj.z - bj.x + 1.0f) * (bj.w - bj.y + 1.0f);
        over = (inter / (ai + aj - inter)) > NMS_THRESH;
      }
      unsigned long long bal = __ballot(over);
      if (lane == 0) s_mask[(size_t)i * words + w] = bal;
    }
  }
  __syncthreads();

  if (t == 0) {
    unsigned long long removed[MAXW];
    for (int w = 0; w < words; ++w) removed[w] = 0ULL;
    int cnt = 0;
    for (int i = 0; i < m; ++i) {
      if (!((removed[i >> 6] >> (i & 63)) & 1ULL)) {
        ++cnt;
        s_keep[i] = (cnt <= PER_CLS_TOPN) ? 1 : 0;
        const unsigned long long* row = s_mask + (size_t)i * words;
        for (int w = 0; w < words; ++w) removed[w] |= row[w];
      } else {
        s_keep[i] = 0;
      }
    }
  }
  __syncthreads();
  for (int i = t; i < m; i += 256) {
    if (s_keep[i]) kept[(size_t)s_idx[i] * NUM_CLS + j] = 1;
  }
}

// ---------------------------------------------------------------------------
// Kernel B2: per-proposal max/argmax over kept classes.  One block per
// proposal; packed u64 max-reduce gives argmax first-max tie-break.
// ---------------------------------------------------------------------------
__global__ __launch_bounds__(256) void argmax_kernel(
    const float* __restrict__ probs, const unsigned char* __restrict__ kept,
    float* __restrict__ score_ws, int* __restrict__ label_ws) {
  int n = blockIdx.x;
  int t = threadIdx.x;
  __shared__ unsigned long long red[256];

  // implicit background entry: value 0.0, label 0 (dist[:,0] == 0 always)
  unsigned long long key = 0x00000000FFFFFFFFULL;
  if (t >= 1 && t < NUM_CLS && kept[n * NUM_CLS + t]) {
    float v = probs[n * NUM_CLS + t];
    key = ((unsigned long long)__float_as_uint(v) << 32) |
          (unsigned)(0xFFFFFFFFu - (unsigned)t);
  }
  red[t] = key;
  __syncthreads();
  for (int s = 128; s > 0; s >>= 1) {
    if (t < s) { unsigned long long o = red[t + s]; if (o > red[t]) red[t] = o; }
    __syncthreads();
  }
  if (t == 0) {
    unsigned long long k = red[0];
    score_ws[n] = __uint_as_float((unsigned)(k >> 32));
    label_ws[n] = (int)(0xFFFFFFFFu - (unsigned)(k & 0xFFFFFFFFULL));
  }
}

// ---------------------------------------------------------------------------
// Kernel C: top-100 via bitonic sort (lax.top_k semantics: value desc,
// index asc on ties), write scores/labels/valid/final_boxes + top_idx/top_m.
// ---------------------------------------------------------------------------
__global__ __launch_bounds__(256) void combine_kernel(
    const float* __restrict__ score_ws, const int* __restrict__ label_ws,
    const float* __restrict__ boxes, float* __restrict__ out,
    int* __restrict__ top_idx_ws, float* __restrict__ top_m_ws) {
  int t = threadIdx.x;
  __shared__ unsigned long long s_key[1024];

  for (int n = t; n < N_PROP; n += 256) {
    float best = score_ws[n];
    float sel = (best > 0.0f) ? best : -1.0f;
    unsigned int sb = __float_as_uint(sel);
    unsigned int mapped = (sb >> 31) ? ~sb : (sb | 0x80000000u);  // sortable
    s_key[n] = ((unsigned long long)(~mapped) << 32) | (unsigned)n;
  }
  for (int n = N_PROP + t; n < 1024; n += 256) s_key[n] = ~0ULL;
  __syncthreads();

  for (int k = 2; k <= 1024; k <<= 1) {
    for (int len = k >> 1; len > 0; len >>= 1) {
      for (int i = t; i < 1024; i += 256) {
        int p2 = i ^ len;
        if (p2 > i) {
          unsigned long long a = s_key[i], b = s_key[p2];
          bool up = ((i & k) == 0);
          if ((a > b) == up) { s_key[i] = b; s_key[p2] = a; }
        }
      }
      __syncthreads();
    }
  }

  if (t < K_OUT) {
    int n = (int)(s_key[t] & 0xFFFFFFFFULL);
    float v = score_ws[n];
    bool valid = v > 0.0f;
    float mm = valid ? 1.0f : 0.0f;
    int glab = label_ws[n];
    out[OF_SC + t] = valid ? v : 0.0f;
    out[OF_LB + t] = (float)(valid ? glab : 0);
    out[OF_VD + t] = mm;
    const float* bp = boxes + (size_t)(n * NUM_CLS + glab) * 4;
    out[OF_BOX + t * 4 + 0] = bp[0] * mm;
    out[OF_BOX + t * 4 + 1] = bp[1] * mm;
    out[OF_BOX + t * 4 + 2] = bp[2] * mm;
    out[OF_BOX + t * 4 + 3] = bp[3] * mm;
    top_idx_ws[t] = n;
    top_m_ws[t] = mm;
  }
}

// ---------------------------------------------------------------------------
// Kernel C2: boxes_per_cls — one block per output row, contiguous row copy.
// ---------------------------------------------------------------------------
__global__ __launch_bounds__(256) void bpc_kernel(
    const float* __restrict__ boxes, const int* __restrict__ top_idx,
    const float* __restrict__ top_m, float* __restrict__ out) {
  int k = blockIdx.x;
  int n = top_idx[k];
  float mm = top_m[k];
  const float4* src = (const float4*)(boxes + (size_t)n * NUM_CLS * 4);
  float4* dst = (float4*)(out + OF_BPC + (size_t)k * NUM_CLS * 4);
  for (int c = threadIdx.x; c < NUM_CLS; c += 256) {
    float4 b = src[c];
    dst[c] = make_float4(b.x * mm, b.y * mm, b.z * mm, b.w * mm);
  }
}

// ---------------------------------------------------------------------------
// Kernel D: gather features rows for the top-100.  One block per output row.
// ---------------------------------------------------------------------------
__global__ __launch_bounds__(256) void gather_features_kernel(
    const float* __restrict__ features, const int* __restrict__ top_idx,
    const float* __restrict__ top_m, float* __restrict__ out) {
  int k = blockIdx.x;
  int n = top_idx[k];
  float mm = top_m[k];
  const float4* src = (const float4*)(features + (size_t)n * FEAT_DIM);
  float4* dst = (float4*)(out + (size_t)k * FEAT_DIM);
  for (int i = threadIdx.x; i < FEAT_DIM / 4; i += 256) {
    float4 v = src[i];
    dst[i] = make_float4(v.x * mm, v.y * mm, v.z * mm, v.w * mm);
  }
}

extern "C" void kernel_launch(void* const* d_in, const int* in_sizes, int n_in,
                              void* d_out, int out_size, void* d_ws, size_t ws_size,
                              hipStream_t stream) {
  const float* features = (const float*)d_in[0];
  const float* logits   = (const float*)d_in[1];
  const float* breg     = (const float*)d_in[2];
  const float* pboxes   = (const float*)d_in[3];
  float* out = (float*)d_out;

  // workspace layout
  float* probs = (float*)d_ws;                              // 600*151 f32
  float* boxes = probs + N_PROP * NUM_CLS;                  // 600*151*4 f32
  unsigned char* kept = (unsigned char*)(boxes + (size_t)N_PROP * NUM_CLS * 4);
  size_t kept_end = (size_t)(kept + (size_t)N_PROP * NUM_CLS);
  float* score_ws = (float*)((kept_end + 15) & ~(size_t)15);  // 600 f32
  int*   label_ws = (int*)(score_ws + N_PROP);                // 600 i32
  int*   top_idx  = label_ws + N_PROP;                        // 128 i32
  float* top_m    = (float*)(top_idx + 128);                  // 128 f32

  hipLaunchKernelGGL(decode_softmax_kernel, dim3(N_PROP), dim3(256), 0, stream,
                     logits, breg, pboxes, probs, boxes, kept);
  hipLaunchKernelGGL(nms_kernel, dim3(NUM_CLS - 1), dim3(256), 0, stream,
                     probs, boxes, kept);
  hipLaunchKernelGGL(argmax_kernel, dim3(N_PROP), dim3(256), 0, stream,
                     probs, kept, score_ws, label_ws);
  hipLaunchKernelGGL(combine_kernel, dim3(1), dim3(256), 0, stream,
                     score_ws, label_ws, boxes, out, top_idx, top_m);
  hipLaunchKernelGGL(bpc_kernel, dim3(K_OUT), dim3(256), 0, stream,
                     boxes, top_idx, top_m, out);
  hipLaunchKernelGGL(gather_features_kernel, dim3(K_OUT), dim3(256), 0, stream,
                     features, top_idx, top_m, out);
}

// Round 10
// 88.356 us; speedup vs baseline: 2.6905x; 1.2819x over previous
//
#include <hip/hip_runtime.h>
#include <hip/hip_bf16.h>
#include <math.h>

#define N_PROP 600
#define NUM_CLS 151
#define FEAT_DIM 4096
#define K_OUT 100
#define SCORE_THRESH 0.05f
#define NMS_THRESH 0.5f
#define PER_CLS_TOPN 300
#define IMG_W 1024.0f
#define IMG_H 768.0f
#define BBOX_CLIP 4.135166556742356f  /* log(1000/16) */
#define MAXW 10                       /* ceil(600/64) */

// out layout (reference return order, all f32):
#define OF_BOX (K_OUT * FEAT_DIM)      /* 409600: final_boxes [100,4]   */
#define OF_SC  (OF_BOX + K_OUT * 4)    /* 410000: final_scores [100]    */
#define OF_LB  (OF_SC + K_OUT)         /* 410100: final_labels [100]    */
#define OF_VD  (OF_LB + K_OUT)         /* 410200: valid_out [100]       */
#define OF_BPC (OF_VD + K_OUT)         /* 410300: boxes_per_cls [100,151,4] */

// ---------------------------------------------------------------------------
// Kernel A: softmax + box decode + clip, one WAVE per proposal (no barriers).
// Also inits packed[n] = {score 0.0, label 0} (background entry of dist).
// ---------------------------------------------------------------------------
__global__ __launch_bounds__(256) void decode_softmax_kernel(
    const float* __restrict__ logits, const float* __restrict__ breg,
    const float* __restrict__ pboxes, float* __restrict__ probs,
    float* __restrict__ boxes, unsigned long long* __restrict__ packed) {
  int wv = threadIdx.x >> 6, lane = threadIdx.x & 63;
  int n = blockIdx.x * 4 + wv;  // grid = 150 -> n < 600 always

  const float* lg = logits + (size_t)n * NUM_CLS;
  int c0 = lane, c1 = lane + 64, c2 = lane + 128;
  float x0 = (c0 < NUM_CLS) ? lg[c0] : -INFINITY;
  float x1 = (c1 < NUM_CLS) ? lg[c1] : -INFINITY;
  float x2 = (c2 < NUM_CLS) ? lg[c2] : -INFINITY;

  float mx = fmaxf(fmaxf(x0, x1), x2);
  for (int off = 32; off > 0; off >>= 1) mx = fmaxf(mx, __shfl_xor(mx, off));

  float e0 = (c0 < NUM_CLS) ? expf(x0 - mx) : 0.0f;
  float e1 = (c1 < NUM_CLS) ? expf(x1 - mx) : 0.0f;
  float e2 = (c2 < NUM_CLS) ? expf(x2 - mx) : 0.0f;
  float sum = e0 + e1 + e2;
  for (int off = 32; off > 0; off >>= 1) sum += __shfl_xor(sum, off);

  // proposal geometry (same for all lanes)
  float b0 = pboxes[n * 4 + 0], b1 = pboxes[n * 4 + 1];
  float b2 = pboxes[n * 4 + 2], b3 = pboxes[n * 4 + 3];
  float w = b2 - b0 + 1.0f, h = b3 - b1 + 1.0f;
  float cx = b0 + 0.5f * w, cy = b1 + 0.5f * h;

  float ee[3] = {e0, e1, e2};
  int cc[3] = {c0, c1, c2};
  for (int q = 0; q < 3; ++q) {
    int c = cc[q];
    if (c < NUM_CLS) {
      probs[(size_t)n * NUM_CLS + c] = ee[q] / sum;
      const float* d = breg + (size_t)n * (NUM_CLS * 4) + c * 4;
      float dx = d[0] / 10.0f, dy = d[1] / 10.0f;
      float dw = fminf(d[2] / 5.0f, BBOX_CLIP);
      float dh = fminf(d[3] / 5.0f, BBOX_CLIP);
      float pcx = dx * w + cx, pcy = dy * h + cy;
      float pw = expf(dw) * w, ph = expf(dh) * h;
      float xx1 = pcx - 0.5f * pw, yy1 = pcy - 0.5f * ph;
      float xx2 = pcx + 0.5f * pw - 1.0f, yy2 = pcy + 0.5f * ph - 1.0f;
      xx1 = fminf(fmaxf(xx1, 0.0f), IMG_W - 1.0f);
      yy1 = fminf(fmaxf(yy1, 0.0f), IMG_H - 1.0f);
      xx2 = fminf(fmaxf(xx2, 0.0f), IMG_W - 1.0f);
      yy2 = fminf(fmaxf(yy2, 0.0f), IMG_H - 1.0f);
      float4* bo = (float4*)(boxes + ((size_t)n * NUM_CLS + c) * 4);
      *bo = make_float4(xx1, yy1, xx2, yy2);
    }
  }
  if (lane == 0) packed[n] = 0x00000000FFFFFFFFULL;  // score 0.0, label 0
}

// ---------------------------------------------------------------------------
// Kernel B: per-class greedy NMS.  One block per class 1..150.
// Compact -> bitonic sort -> wave-ballot IoU mask -> serial bitmask scan
// (matches reference: suppression uses ALL keeps; 300-cap masks flags only).
// Kept entries fold directly into packed[n] via u64 atomicMax:
//   key = (prob_bits << 32) | ~class   (argmax first-max tie-break).
// ---------------------------------------------------------------------------
__global__ __launch_bounds__(256) void nms_kernel(
    const float* __restrict__ probs, const float* __restrict__ boxes,
    unsigned long long* __restrict__ packed) {
  int j = blockIdx.x + 1;  // classes 1..150
  int t = threadIdx.x;

  __shared__ int s_m;
  // LDS pool: [0,48000) keys (phase 1, 1024*8B) then IoU mask (600*10*8B);
  // [48000,57600) boxes float4; [57600,58800) idx u16; [58800,59440) keep u8;
  // [59440,61840) prob f32
  alignas(16) __shared__ unsigned char pool[48000 + 9600 + 1280 + 640 + 2400];
  unsigned long long* s_key  = (unsigned long long*)pool;
  unsigned long long* s_mask = (unsigned long long*)pool;
  float4*             s_box  = (float4*)(pool + 48000);
  unsigned short*     s_idx  = (unsigned short*)(pool + 48000 + 9600);
  unsigned char*      s_keep = pool + 48000 + 9600 + 1280;
  float*              s_prob = (float*)(pool + 48000 + 9600 + 1280 + 640);

  if (t == 0) s_m = 0;
  __syncthreads();
  for (int n = t; n < N_PROP; n += 256) {
    float p = probs[(size_t)n * NUM_CLS + j];
    if (p > SCORE_THRESH) {
      int pos = atomicAdd(&s_m, 1);
      // score desc, index asc when sorted ascending (scores are positive)
      s_key[pos] = ((unsigned long long)(~__float_as_uint(p)) << 32) | (unsigned)n;
    }
  }
  __syncthreads();
  int m = s_m;
  if (m == 0) return;

  int sz = 1;
  while (sz < m) sz <<= 1;
  for (int i = m + t; i < sz; i += 256) s_key[i] = ~0ULL;
  __syncthreads();

  for (int k = 2; k <= sz; k <<= 1) {
    for (int len = k >> 1; len > 0; len >>= 1) {
      for (int i = t; i < sz; i += 256) {
        int p2 = i ^ len;
        if (p2 > i) {
          unsigned long long a = s_key[i], b = s_key[p2];
          bool up = ((i & k) == 0);
          if ((a > b) == up) { s_key[i] = b; s_key[p2] = a; }
        }
      }
      __syncthreads();
    }
  }

  // extract idx/prob + load sorted boxes (mask writes clobber keys after sync)
  for (int i = t; i < m; i += 256) {
    unsigned long long k = s_key[i];
    int n = (int)(k & 0xFFFFFFFFULL);
    s_idx[i] = (unsigned short)n;
    s_prob[i] = __uint_as_float(~(unsigned)(k >> 32));
    s_box[i] = *(const float4*)(boxes + ((size_t)n * NUM_CLS + j) * 4);
  }
  __syncthreads();

  int words = (m + 63) >> 6;
  int wave = t >> 6, lane = t & 63;
  for (int i = wave; i < m; i += 4) {
    float4 bi = s_box[i];
    float ai = (bi.z - bi.x + 1.0f) * (bi.w - bi.y + 1.0f);
    for (int w = 0; w < words; ++w) {
      int jj = (w << 6) + lane;
      bool over = false;
      if (jj < m) {
        float4 bj = s_box[jj];
        float xx1 = fmaxf(bi.x, bj.x), yy1 = fmaxf(bi.y, bj.y);
        float xx2 = fminf(bi.z, bj.z), yy2 = fminf(bi.w, bj.w);
        float iw = fmaxf(xx2 - xx1 + 1.0f, 0.0f);
        float ih = fmaxf(yy2 - yy1 + 1.0f, 0.0f);
        float inter = iw * ih;
        float aj = (bj.z - bj.x + 1.0f) * (bj.w - bj.y + 1.0f);
        over = (inter / (ai + aj - inter)) > NMS_THRESH;
      }
      unsigned long long bal = __ballot(over);
      if (lane == 0) s_mask[(size_t)i * words + w] = bal;
    }
  }
  __syncthreads();

  if (t == 0) {
    unsigned long long removed[MAXW];
    for (int w = 0; w < words; ++w) removed[w] = 0ULL;
    int cnt = 0;
    for (int i = 0; i < m; ++i) {
      if (!((removed[i >> 6] >> (i & 63)) & 1ULL)) {
        ++cnt;
        s_keep[i] = (cnt <= PER_CLS_TOPN) ? 1 : 0;
        const unsigned long long* row = s_mask + (size_t)i * words;
        for (int w = 0; w < words; ++w) removed[w] |= row[w];
      } else {
        s_keep[i] = 0;
      }
    }
  }
  __syncthreads();
  for (int i = t; i < m; i += 256) {
    if (s_keep[i]) {
      unsigned long long key =
          ((unsigned long long)__float_as_uint(s_prob[i]) << 32) |
          (unsigned)(0xFFFFFFFFu - (unsigned)j);
      atomicMax(&packed[s_idx[i]], key);
    }
  }
}

// ---------------------------------------------------------------------------
// Kernel C: finalize — read packed[600], bitonic top-100 (lax.top_k
// semantics: value desc, index asc ties), write scores/labels/valid/
// final_boxes + top_idx/top_m.  One 1024-thread block.
// ---------------------------------------------------------------------------
__global__ __launch_bounds__(1024) void finalize_kernel(
    const unsigned long long* __restrict__ packed,
    const float* __restrict__ boxes, float* __restrict__ out,
    int* __restrict__ top_idx_ws, float* __restrict__ top_m_ws) {
  int t = threadIdx.x;
  __shared__ unsigned long long s_key[1024];
  __shared__ float s_score[N_PROP];
  __shared__ int s_label[N_PROP];

  if (t < N_PROP) {
    unsigned long long pk = packed[t];
    float best = __uint_as_float((unsigned)(pk >> 32));
    int lab = (int)(0xFFFFFFFFu - (unsigned)(pk & 0xFFFFFFFFULL));
    s_score[t] = best;
    s_label[t] = lab;
    float sel = (best > 0.0f) ? best : -1.0f;
    unsigned int sb = __float_as_uint(sel);
    unsigned int mapped = (sb >> 31) ? ~sb : (sb | 0x80000000u);  // sortable
    s_key[t] = ((unsigned long long)(~mapped) << 32) | (unsigned)t;
  } else {
    s_key[t] = ~0ULL;
  }
  __syncthreads();

  for (int k = 2; k <= 1024; k <<= 1) {
    for (int len = k >> 1; len > 0; len >>= 1) {
      int p2 = t ^ len;
      if (p2 > t) {
        unsigned long long a = s_key[t], b = s_key[p2];
        bool up = ((t & k) == 0);
        if ((a > b) == up) { s_key[t] = b; s_key[p2] = a; }
      }
      __syncthreads();
    }
  }

  if (t < K_OUT) {
    int n = (int)(s_key[t] & 0xFFFFFFFFULL);
    float v = s_score[n];
    bool valid = v > 0.0f;
    float mm = valid ? 1.0f : 0.0f;
    int glab = s_label[n];
    out[OF_SC + t] = valid ? v : 0.0f;
    out[OF_LB + t] = (float)(valid ? glab : 0);
    out[OF_VD + t] = mm;
    const float* bp = boxes + ((size_t)n * NUM_CLS + glab) * 4;
    out[OF_BOX + t * 4 + 0] = bp[0] * mm;
    out[OF_BOX + t * 4 + 1] = bp[1] * mm;
    out[OF_BOX + t * 4 + 2] = bp[2] * mm;
    out[OF_BOX + t * 4 + 3] = bp[3] * mm;
    top_idx_ws[t] = n;
    top_m_ws[t] = mm;
  }
}

// ---------------------------------------------------------------------------
// Kernel D: fused gathers.  Blocks 0..99: features row (4096 f32).
// Blocks 100..199: boxes_per_cls row (151 float4).
// ---------------------------------------------------------------------------
__global__ __launch_bounds__(256) void gather_kernel(
    const float* __restrict__ features, const float* __restrict__ boxes,
    const int* __restrict__ top_idx, const float* __restrict__ top_m,
    float* __restrict__ out) {
  int b = blockIdx.x;
  if (b < K_OUT) {
    int k = b;
    int n = top_idx[k];
    float mm = top_m[k];
    const float4* src = (const float4*)(features + (size_t)n * FEAT_DIM);
    float4* dst = (float4*)(out + (size_t)k * FEAT_DIM);
    for (int i = threadIdx.x; i < FEAT_DIM / 4; i += 256) {
      float4 v = src[i];
      dst[i] = make_float4(v.x * mm, v.y * mm, v.z * mm, v.w * mm);
    }
  } else {
    int k = b - K_OUT;
    int n = top_idx[k];
    float mm = top_m[k];
    const float4* src = (const float4*)(boxes + (size_t)n * NUM_CLS * 4);
    float4* dst = (float4*)(out + OF_BPC + (size_t)k * NUM_CLS * 4);
    for (int c = threadIdx.x; c < NUM_CLS; c += 256) {
      float4 v = src[c];
      dst[c] = make_float4(v.x * mm, v.y * mm, v.z * mm, v.w * mm);
    }
  }
}

extern "C" void kernel_launch(void* const* d_in, const int* in_sizes, int n_in,
                              void* d_out, int out_size, void* d_ws, size_t ws_size,
                              hipStream_t stream) {
  const float* features = (const float*)d_in[0];
  const float* logits   = (const float*)d_in[1];
  const float* breg     = (const float*)d_in[2];
  const float* pboxes   = (const float*)d_in[3];
  float* out = (float*)d_out;

  // workspace layout (16B-aligned chunks)
  float* probs = (float*)d_ws;                                   // 600*151 f32
  float* boxes = probs + N_PROP * NUM_CLS;                       // 600*151*4 f32
  unsigned long long* packed =
      (unsigned long long*)(boxes + (size_t)N_PROP * NUM_CLS * 4);  // 600 u64
  int*   top_idx = (int*)(packed + N_PROP);                      // 128 i32
  float* top_m   = (float*)(top_idx + 128);                      // 128 f32

  hipLaunchKernelGGL(decode_softmax_kernel, dim3(N_PROP / 4), dim3(256), 0,
                     stream, logits, breg, pboxes, probs, boxes, packed);
  hipLaunchKernelGGL(nms_kernel, dim3(NUM_CLS - 1), dim3(256), 0, stream,
                     probs, boxes, packed);
  hipLaunchKernelGGL(finalize_kernel, dim3(1), dim3(1024), 0, stream,
                     packed, boxes, out, top_idx, top_m);
  hipLaunchKernelGGL(gather_kernel, dim3(2 * K_OUT), dim3(256), 0, stream,
                     features, boxes, top_idx, top_m, out);
}